// Round 4
// baseline (45.850 us; speedup 1.0000x reference)
//
#include <hip/hip_runtime.h>

// LIF forward scan, B=65536 rows x L=400 steps.
// Outputs (concatenated float32 in d_out):
//   [0,              B*L)    spikes (exactly 0.0/1.0)
//   [B*L,        B*L + B)    hard_latency (first spike index, or L) as float
//   [B*L + B,  B*L + 2*B)    soft_latency = sum(s*t) / (sum(s) + 1e-6)
//
// R3: single-wave blocks, ZERO barriers (LDS ops within one wavefront execute
// in order; __syncthreads' implicit vmcnt(0) drain was killing the prefetch).
// 2-deep register prefetch (chunks c+2, c+3 in flight) + double-buffered LDS
// tiles; the compiler emits a *counted* vmcnt at stage time, leaving the
// newer chunk's loads in flight across the whole compute phase.

constexpr int Bsz   = 65536;
constexpr int Lsz   = 400;
constexpr int ROWS  = 64;           // ONE wave per block — barrier-free LDS
constexpr int TC    = 40;           // timesteps per chunk
constexpr int NCH   = Lsz / TC;     // 10 chunks (even, required by ch+=2 loop)
constexpr int STRIDE = TC + 1;      // 41: (tid*41+c)%32 = 2 lanes/bank -> free
constexpr int V4    = TC / 4;       // 10 float4 per row-chunk == per thread

__global__ __launch_bounds__(ROWS)
void lif_kernel(const float* __restrict__ I, float* __restrict__ out)
{
    __shared__ float tile[2][ROWS * STRIDE];   // 2 x 10,496 B

    const int tid = threadIdx.x;
    const int rb  = blockIdx.x * ROWS;
    const int row = rb + tid;

    const float* Ib = I   + (size_t)rb * Lsz;
    float*       Sb = out + (size_t)rb * Lsz;

    float4 regA[V4], regB[V4];

    auto glb_load = [&](int ch, float4* rg) {
#pragma unroll
        for (int it = 0; it < V4; ++it) {
            const int idx = it * ROWS + tid;
            const int r   = idx / V4;
            const int c4  = idx % V4;
            rg[it] = *reinterpret_cast<const float4*>(Ib + r * Lsz + ch * TC + c4 * 4);
        }
    };
    auto stage = [&](const float4* rg, float* tl) {
#pragma unroll
        for (int it = 0; it < V4; ++it) {
            const int idx = it * ROWS + tid;
            const int r   = idx / V4;
            const int c4  = idx % V4;
            float* d = &tl[r * STRIDE + c4 * 4];
            d[0] = rg[it].x; d[1] = rg[it].y; d[2] = rg[it].z; d[3] = rg[it].w;
        }
    };

    float v     = 0.0f;
    float theta = 1.0f;
    int   allow = 0;                // earliest step index that may spike
    int   first = Lsz;
    float cnt   = 0.0f;
    float swt   = 0.0f;

    // compute chunk ch from LDS tile tl; spikes overwrite input in place
    auto body = [&](int ch, float* tl) {
        float* myrow = &tl[tid * STRIDE];
        float cnt_l = 0.0f, swt_l = 0.0f;
        const int t0 = ch * TC;
#pragma unroll
        for (int c = 0; c < TC; ++c) {
            const int t = t0 + c;               // uniform (scalar) per step
            const float It = myrow[c];
            v = __builtin_fmaf(v, 0.95f, It);   // v += -v/20 + I
            const bool hard = (v >= theta) & (t >= allow);
            const float s   = hard ? 1.0f : 0.0f;
            v     = hard ? 0.0f : v;
            theta = __builtin_fmaf(theta, 0.98f, hard ? 0.52f : 0.02f);
            allow = hard ? (t + 6) : allow;     // refractory: 5 blocked steps
            myrow[c] = s;
            cnt_l += s;
            swt_l = __builtin_fmaf(s, (float)c, swt_l);   // literal c
            first = hard ? min(first, t) : first;
        }
        swt = __builtin_fmaf(cnt_l, (float)t0, swt + swt_l);
        cnt += cnt_l;
    };
    auto store = [&](int ch, const float* tl) {
        const int t0 = ch * TC;
#pragma unroll
        for (int it = 0; it < V4; ++it) {
            const int idx = it * ROWS + tid;
            const int r   = idx / V4;
            const int c4  = idx % V4;
            const float* sp = &tl[r * STRIDE + c4 * 4];
            const float4 vv = make_float4(sp[0], sp[1], sp[2], sp[3]);
            *reinterpret_cast<float4*>(Sb + r * Lsz + t0 + c4 * 4) = vv;
        }
    };

    // prologue: chunks 0,1 in flight; stage 0 (counted vmcnt leaves 1 in flight); issue 2
    glb_load(0, regA);
    glb_load(1, regB);
    stage(regA, tile[0]);
    glb_load(2, regA);

    for (int ch = 0; ch < NCH; ch += 2) {
        // even chunk: compute/store tile0; bring chunk ch+1 into tile1; issue ch+3
        body(ch, tile[0]);
        store(ch, tile[0]);
        stage(regB, tile[1]);                   // waits only on regB's loads
        if (ch + 3 < NCH) glb_load(ch + 3, regB);
        // odd chunk: compute/store tile1; bring chunk ch+2 into tile0; issue ch+4
        body(ch + 1, tile[1]);
        store(ch + 1, tile[1]);
        if (ch + 2 < NCH) stage(regA, tile[0]);
        if (ch + 4 < NCH) glb_load(ch + 4, regA);
    }

    out[(size_t)Bsz * Lsz + row]       = (float)first;
    out[(size_t)Bsz * Lsz + Bsz + row] = swt / (cnt + 1e-6f);
}

extern "C" void kernel_launch(void* const* d_in, const int* in_sizes, int n_in,
                              void* d_out, int out_size, void* d_ws, size_t ws_size,
                              hipStream_t stream)
{
    const float* I = (const float*)d_in[0];
    float* out = (float*)d_out;
    lif_kernel<<<dim3(Bsz / ROWS), dim3(ROWS), 0, stream>>>(I, out);
}

// Round 5
// 41.941 us; speedup vs baseline: 1.0932x; 1.0932x over previous
//
#include <hip/hip_runtime.h>

// LIF forward scan, B=65536 rows x L=400 steps.
// Outputs (concatenated float32 in d_out):
//   [0,              B*L)    spikes (exactly 0.0/1.0)
//   [B*L,        B*L + B)    hard_latency (first spike index, or L) as float
//   [B*L + B,  B*L + 2*B)    soft_latency = sum(s*t) / (sum(s) + 1e-6)
//
// R4: input goes DIRECTLY to registers (each thread reads its own row,
// 2 chunks deep). No input-side LDS, no stage() step -> the only vmcnt
// waits are load-uses, statically countable past younger stores; the wave
// never waits on store retirement (CDNA vmcnt counts stores too — R2/R3
// both serialized on store drain once per chunk).
// Output keeps the LDS transpose (stride 41, conflict-free) for coalesced
// float4 spike stores.

constexpr int Bsz   = 65536;
constexpr int Lsz   = 400;
constexpr int ROWS  = 64;           // ONE wave per block — barrier-free LDS
constexpr int TC    = 40;           // timesteps per chunk
constexpr int NCH   = Lsz / TC;     // 10 chunks (even; loop steps by 2)
constexpr int STRIDE = TC + 1;      // 41: column access = 2 lanes/bank -> free
constexpr int V4    = TC / 4;       // 10 float4 per chunk per thread

__global__ __launch_bounds__(ROWS)
void lif_kernel(const float* __restrict__ I, float* __restrict__ out)
{
    __shared__ float tile[ROWS * STRIDE];   // 10,496 B (output transpose only)

    const int tid = threadIdx.x;
    const int rb  = blockIdx.x * ROWS;
    const int row = rb + tid;

    const float* Irow = I   + (size_t)row * Lsz;   // this thread's own row
    float*       Sb   = out + (size_t)rb  * Lsz;

    float4 regA[V4], regB[V4];

    auto glb_load = [&](int ch, float4* rg) {
#pragma unroll
        for (int it = 0; it < V4; ++it)
            rg[it] = *reinterpret_cast<const float4*>(Irow + ch * TC + it * 4);
    };

    float v     = 0.0f;
    float theta = 1.0f;
    int   allow = 0;                // earliest step index that may spike
    int   first = Lsz;
    float cnt   = 0.0f;
    float swt   = 0.0f;

    auto body = [&](int ch, const float4* rg) {
        float* myrow = &tile[tid * STRIDE];
        float cnt_l = 0.0f, swt_l = 0.0f;
        const int t0 = ch * TC;

        auto step = [&](float It, int c) {
            const int t = t0 + c;               // uniform per step
            v = __builtin_fmaf(v, 0.95f, It);   // v += -v/20 + I
            const bool hard = (v >= theta) & (t >= allow);
            const float s   = hard ? 1.0f : 0.0f;
            v     = hard ? 0.0f : v;
            theta = __builtin_fmaf(theta, 0.98f, hard ? 0.52f : 0.02f);
            allow = hard ? (t + 6) : allow;
            myrow[c] = s;
            cnt_l += s;
            swt_l = __builtin_fmaf(s, (float)c, swt_l);
            first = hard ? min(first, t) : first;   // once set, stays (t increasing)
        };

#pragma unroll
        for (int c4 = 0; c4 < V4; ++c4) {
            const float4 q = rg[c4];
            step(q.x, c4 * 4 + 0);
            step(q.y, c4 * 4 + 1);
            step(q.z, c4 * 4 + 2);
            step(q.w, c4 * 4 + 3);
        }
        swt = __builtin_fmaf(cnt_l, (float)t0, swt + swt_l);
        cnt += cnt_l;
    };

    auto store = [&](int ch) {
        const int t0 = ch * TC;
#pragma unroll
        for (int it = 0; it < V4; ++it) {
            const int idx = it * ROWS + tid;
            const int r   = idx / V4;
            const int c4  = idx % V4;
            const float* sp = &tile[r * STRIDE + c4 * 4];
            const float4 vv = make_float4(sp[0], sp[1], sp[2], sp[3]);
            *reinterpret_cast<float4*>(Sb + r * Lsz + t0 + c4 * 4) = vv;
        }
    };

    // 2-deep prefetch: chunks ch and ch+1 in regs; reload each buffer
    // immediately after its body consumes it (cover ~= 1 body + 2 stores).
    glb_load(0, regA);
    glb_load(1, regB);

    for (int ch = 0; ch < NCH; ch += 2) {
        body(ch, regA);
        if (ch + 2 < NCH) glb_load(ch + 2, regA);
        store(ch);
        body(ch + 1, regB);
        if (ch + 3 < NCH) glb_load(ch + 3, regB);
        store(ch + 1);
    }

    out[(size_t)Bsz * Lsz + row]       = (float)first;
    out[(size_t)Bsz * Lsz + Bsz + row] = swt / (cnt + 1e-6f);
}

extern "C" void kernel_launch(void* const* d_in, const int* in_sizes, int n_in,
                              void* d_out, int out_size, void* d_ws, size_t ws_size,
                              hipStream_t stream)
{
    const float* I = (const float*)d_in[0];
    float* out = (float*)d_out;
    lif_kernel<<<dim3(Bsz / ROWS), dim3(ROWS), 0, stream>>>(I, out);
}